// Round 1
// baseline (683.774 us; speedup 1.0000x reference)
//
#include <hip/hip_runtime.h>
#include <stdint.h>

typedef unsigned long long u64;

// workspace layout (bytes)
//  g      : u8  [16][512][512]           @ 0        (4 MiB)
//  magdir : u16 [16][512][512]           @ 4 MiB    (8 MiB)   mag(11b) | dir<<12
//  weak   : u64 [16][512][8]             @ 12 MiB   (512 KiB)
//  strong : u64 [16][512][8]             @ 12.5 MiB (512 KiB)
//  edge   : u64 [16][512][8]             @ 13 MiB   (512 KiB)
#define MD_OFF   (4ull << 20)
#define WK_OFF   (12ull << 20)
#define ST_OFF   ((12ull << 20) + (512ull << 10))
#define ED_OFF   ((12ull << 20) + (1024ull << 10))

// ---------------- K1: gray = floor(clip(0.2989 x0 + 0.587 x1 + 0.114 x2)) ----
__global__ __launch_bounds__(256) void k_gray(const float* __restrict__ x,
                                              unsigned char* __restrict__ g) {
#pragma clang fp contract(off)
    const float C0 = (float)0.2989, C1 = (float)0.587, C2 = (float)0.114;
    int i   = blockIdx.x * 256 + threadIdx.x;   // 1,048,576 quads total
    int b   = i >> 16;                          // 65536 quads / image
    int rem = i & 65535;                        // h*128 + wq
    const float* xb = x + (size_t)b * 786432 + (size_t)rem * 4;
    float4 r0 = *(const float4*)(xb);
    float4 r1 = *(const float4*)(xb + 262144);
    float4 r2 = *(const float4*)(xb + 524288);
    float g0 = C0 * r0.x + C1 * r1.x + C2 * r2.x;   // ((a+b)+c) like numpy
    float g1 = C0 * r0.y + C1 * r1.y + C2 * r2.y;
    float g2 = C0 * r0.z + C1 * r1.z + C2 * r2.z;
    float g3 = C0 * r0.w + C1 * r1.w + C2 * r2.w;
    g0 = floorf(fminf(fmaxf(g0, 0.0f), 255.0f));
    g1 = floorf(fminf(fmaxf(g1, 0.0f), 255.0f));
    g2 = floorf(fminf(fmaxf(g2, 0.0f), 255.0f));
    g3 = floorf(fminf(fmaxf(g3, 0.0f), 255.0f));
    uchar4 st = make_uchar4((unsigned char)g0, (unsigned char)g1,
                            (unsigned char)g2, (unsigned char)g3);
    *(uchar4*)(g + (size_t)b * 262144 + (size_t)rem * 4) = st;
}

// ---------------- K2: Sobel (edge-replicate pad), mag = |gx|+|gy|, dir code --
__global__ __launch_bounds__(256) void k_sobel(const unsigned char* __restrict__ g,
                                               unsigned short* __restrict__ magdir) {
    const float TG22f = (float)0.4142135623730951;
    const float TG67f = (float)2.414213562373095;
    int i = blockIdx.x * 256 + threadIdx.x;     // 4,194,304 pixels
    int b = i >> 18;
    int r = (i >> 9) & 511;
    int w = i & 511;
    const unsigned char* gb = g + (size_t)b * 262144;
    int rm = r > 0 ? r - 1 : 0, rp = r < 511 ? r + 1 : 511;
    int wm = w > 0 ? w - 1 : 0, wp = w < 511 ? w + 1 : 511;
    int a00 = gb[rm * 512 + wm], a01 = gb[rm * 512 + w], a02 = gb[rm * 512 + wp];
    int a10 = gb[r  * 512 + wm],                          a12 = gb[r  * 512 + wp];
    int a20 = gb[rp * 512 + wm], a21 = gb[rp * 512 + w],  a22 = gb[rp * 512 + wp];
    int gx = a02 + 2 * a12 + a22 - a00 - 2 * a10 - a20;
    int gy = a20 + 2 * a21 + a22 - a00 - 2 * a01 - a02;
    int ax = gx < 0 ? -gx : gx;
    int ay = gy < 0 ? -gy : gy;
    int mag = ax + ay;                           // <= 2040, exact
    float fax = (float)ax, fay = (float)ay;
    unsigned dir;
    if (fay <= TG22f * fax)      dir = 0u;                       // horiz
    else if (fay > TG67f * fax)  dir = 1u;                       // vert
    else                         dir = (gx * gy >= 0) ? 2u : 3u; // diag
    magdir[i] = (unsigned short)(mag | (dir << 12));
}

// ---------------- K3: NMS + thresholds, ballot-pack weak/strong bitmasks -----
__global__ __launch_bounds__(256) void k_nms(const unsigned short* __restrict__ magdir,
                                             u64* __restrict__ weakw,
                                             u64* __restrict__ strongw) {
    int i = blockIdx.x * 256 + threadIdx.x;
    int b = i >> 18;
    int r = (i >> 9) & 511;
    int w = i & 511;
    const unsigned short* mb = magdir + (size_t)b * 262144;
    int md  = mb[r * 512 + w];
    int mag = md & 0x7FF;
    int dir = md >> 12;
    auto ldm = [&](int rr, int ww) -> int {
        if ((unsigned)rr > 511u || (unsigned)ww > 511u) return 0;  // zero pad
        return (int)(mb[rr * 512 + ww] & 0x7FF);
    };
    int n1, n2;
    if (dir == 0)      { n1 = ldm(r, w + 1);     n2 = ldm(r, w - 1); }
    else if (dir == 1) { n1 = ldm(r - 1, w);     n2 = ldm(r + 1, w); }
    else if (dir == 2) { n1 = ldm(r - 1, w - 1); n2 = ldm(r + 1, w + 1); }
    else               { n1 = ldm(r - 1, w + 1); n2 = ldm(r + 1, w - 1); }
    bool keep = (mag > n1) && (mag >= n2);
    int nms = keep ? mag : 0;
    u64 wb = __ballot(nms > 50);
    u64 sb = __ballot(nms > 150);
    int widx = ((b << 9) + r) * 8 + (w >> 6);
    int lane = threadIdx.x & 63;
    if (lane == 0) weakw[widx]   = wb;
    else if (lane == 1) strongw[widx] = sb;
}

// ---------------- K4: hysteresis flood fill (one block per image) ------------
__device__ inline u64 upfill(u64 w, u64 s) {           // s subset of w
    return ((((w + s) ^ w) & w) | s);                  // fill run bits >= lowest seed
}
__device__ inline u64 runfill(u64 w, u64 s) {          // full in-run fill
    u64 u = upfill(w, s);
    u64 d = __brevll(upfill(__brevll(w), __brevll(s)));
    return u | d;
}

__global__ __launch_bounds__(512) void k_hyst(const u64* __restrict__ weakg,
                                              const u64* __restrict__ strongg,
                                              u64* __restrict__ edgeg) {
    __shared__ u64 cur[4096];     // 512 rows x 8 word-cols, 32 KiB
    __shared__ int sflag;
    int b = blockIdx.x;
    int t = threadIdx.x;
    const u64* wk = weakg + (size_t)b * 4096;
    const u64* st = strongg + (size_t)b * 4096;
    int c  = t & 7;               // word column 0..7
    int r0 = (t >> 3) * 8;        // 8 rows per thread
    u64 wreg[8];
#pragma unroll
    for (int j = 0; j < 8; ++j) {
        int idx = (r0 + j) * 8 + c;
        wreg[j] = wk[idx];
        cur[idx] = st[idx];       // strong subset weak -> invariant cur ⊆ weak
    }
    __syncthreads();

    for (int it = 0;; ++it) {
        if (t == 0) sflag = 0;
        __syncthreads();
        bool ch = false;
        bool down = (it & 1) == 0;
        u64 carry = 0;
        for (int k = 0; k < 8; ++k) {
            int j = down ? k : 7 - k;
            int r = r0 + j;
            int idx = r * 8 + c;
            u64 wv = wreg[j];
            u64 self = cur[idx];
            if (self == wv) { carry = self; continue; }   // saturated
            u64 um = (r > 0)   ? ((down && k > 0)  ? carry : cur[idx - 8]) : 0;
            u64 dm = (r < 511) ? ((!down && k > 0) ? carry : cur[idx + 8]) : 0;
            u64 lor = 0, ror_ = 0;
            if (c > 0) {
                u64 lm = cur[idx - 1];
                u64 lu = (r > 0)   ? cur[idx - 9] : 0;
                u64 ld = (r < 511) ? cur[idx + 7] : 0;
                lor = lm | lu | ld;
            }
            if (c < 7) {
                u64 rm = cur[idx + 1];
                u64 ru = (r > 0)   ? cur[idx - 7] : 0;
                u64 rd = (r < 511) ? cur[idx + 9] : 0;
                ror_ = rm | ru | rd;
            }
            u64 vert = um | dm | self;
            u64 dil = vert | (vert << 1) | (vert >> 1) | (lor >> 63) | (ror_ << 63);
            u64 nv = self | (wv & dil);
            nv = runfill(wv, nv);            // instant in-word horizontal fill
            carry = nv;
            if (nv != self) { cur[idx] = nv; ch = true; }
        }
        if (ch) sflag = 1;
        __syncthreads();
        if (!sflag) break;                   // uniform: read between barriers
        __syncthreads();                     // protect read vs next reset
    }

    u64* eg = edgeg + (size_t)b * 4096;
#pragma unroll
    for (int j = 0; j < 8; ++j) {
        int idx = (r0 + j) * 8 + c;
        eg[idx] = cur[idx];
    }
}

// ---------------- K5: out[b,o,h,w] = relu(W.[x0,x1,x2,edge] + b) -------------
__global__ __launch_bounds__(256) void k_out(const float* __restrict__ x,
                                             const float* __restrict__ Wm,
                                             const float* __restrict__ bv,
                                             const u64* __restrict__ edgeg,
                                             float* __restrict__ out) {
    __shared__ float sW[128];
    __shared__ float sb[32];
    if (threadIdx.x < 128) sW[threadIdx.x] = Wm[threadIdx.x];
    if (threadIdx.x < 32)  sb[threadIdx.x] = bv[threadIdx.x];
    __syncthreads();
    int i   = blockIdx.x * 256 + threadIdx.x;   // 1,048,576 quads
    int b   = i >> 16;
    int rem = i & 65535;                        // h*128 + wq
    size_t pix = (size_t)rem * 4;               // h*512 + wq*4
    const float* xb = x + (size_t)b * 786432;
    float4 x0 = *(const float4*)(xb + pix);
    float4 x1 = *(const float4*)(xb + 262144 + pix);
    float4 x2 = *(const float4*)(xb + 524288 + pix);
    int r  = rem >> 7;
    int wq = rem & 127;
    u64 ew = edgeg[(((size_t)b * 512 + r) * 8) + (wq >> 4)];
    int sh = (wq & 15) * 4;
    float e0 = ((ew >> (sh + 0)) & 1ull) ? 255.0f : 0.0f;
    float e1 = ((ew >> (sh + 1)) & 1ull) ? 255.0f : 0.0f;
    float e2 = ((ew >> (sh + 2)) & 1ull) ? 255.0f : 0.0f;
    float e3 = ((ew >> (sh + 3)) & 1ull) ? 255.0f : 0.0f;
    float* ob = out + (size_t)b * 32 * 262144 + pix;
#pragma unroll 4
    for (int o = 0; o < 32; ++o) {
        float w0 = sW[o * 4 + 0], w1 = sW[o * 4 + 1];
        float w2 = sW[o * 4 + 2], w3 = sW[o * 4 + 3];
        float bb = sb[o];
        float4 v;
        v.x = fmaxf(w0 * x0.x + w1 * x1.x + w2 * x2.x + w3 * e0 + bb, 0.0f);
        v.y = fmaxf(w0 * x0.y + w1 * x1.y + w2 * x2.y + w3 * e1 + bb, 0.0f);
        v.z = fmaxf(w0 * x0.z + w1 * x1.z + w2 * x2.z + w3 * e2 + bb, 0.0f);
        v.w = fmaxf(w0 * x0.w + w1 * x1.w + w2 * x2.w + w3 * e3 + bb, 0.0f);
        *(float4*)(ob + (size_t)o * 262144) = v;
    }
}

extern "C" void kernel_launch(void* const* d_in, const int* in_sizes, int n_in,
                              void* d_out, int out_size, void* d_ws, size_t ws_size,
                              hipStream_t stream) {
    const float* x  = (const float*)d_in[0];   // (16,3,512,512)
    const float* Wm = (const float*)d_in[1];   // (32,4)
    const float* bv = (const float*)d_in[2];   // (32,)
    float* out = (float*)d_out;                // (16,32,512,512)
    char* ws = (char*)d_ws;

    unsigned char*  g      = (unsigned char*)(ws);
    unsigned short* magdir = (unsigned short*)(ws + MD_OFF);
    u64* weakw   = (u64*)(ws + WK_OFF);
    u64* strongw = (u64*)(ws + ST_OFF);
    u64* edgew   = (u64*)(ws + ED_OFF);

    k_gray<<<4096, 256, 0, stream>>>(x, g);
    k_sobel<<<16384, 256, 0, stream>>>(g, magdir);
    k_nms<<<16384, 256, 0, stream>>>(magdir, weakw, strongw);
    k_hyst<<<16, 512, 0, stream>>>(weakw, strongw, edgew);
    k_out<<<4096, 256, 0, stream>>>(x, Wm, bv, edgew, out);
}